// Round 1
// baseline (4460.672 us; speedup 1.0000x reference)
//
#include <hip/hip_runtime.h>
#include <math.h>

namespace {
constexpr int kD   = 512;    // model dim
constexpr int kN   = 8192;   // B*S rows
constexpr int kS   = 1024;   // sequence
constexpr int kHD  = 64;     // head dim
constexpr int kFF  = 2048;   // ffn dim
constexpr int kSL  = 512;    // slots
constexpr int kOUT = 32;     // out per slot
}

// ------------------------------------------------------------------ GEMM
// C[M,N] = act(alpha*(A@B) + bias), A row-major [M,K], B row-major [K,N]
template<int RELU, int HAS_BIAS>
__global__ __launch_bounds__(256)
void gemm_k(const float* __restrict__ A, const float* __restrict__ B,
            const float* __restrict__ bias, float* __restrict__ C,
            int M, int N, int K, float alpha)
{
    constexpr int BM = 128, BN = 128, BK = 16;
    __shared__ float As[BK][BM + 4];
    __shared__ float Bs[BK][BN];
    const int tid = threadIdx.x;
    const int tr = tid >> 4;          // 0..15
    const int tc = tid & 15;          // 0..15
    const int bx = blockIdx.x, by = blockIdx.y;
    const float* Ab = A + (size_t)by * BM * K;
    const float* Bb = B + (size_t)bx * BN;
    const int ar  = tid >> 2;         // 0..63
    const int ac4 = (tid & 3) << 2;   // 0,4,8,12
    const int br  = tid >> 5;         // 0..7
    const int bc4 = (tid & 31) << 2;  // 0..124
    float acc[8][8];
#pragma unroll
    for (int i = 0; i < 8; ++i)
#pragma unroll
        for (int j = 0; j < 8; ++j) acc[i][j] = 0.f;

    for (int k0 = 0; k0 < K; k0 += BK) {
        const float4 a0 = *(const float4*)(Ab + (size_t)ar * K + k0 + ac4);
        const float4 a1 = *(const float4*)(Ab + (size_t)(ar + 64) * K + k0 + ac4);
        const float4 b0 = *(const float4*)(Bb + (size_t)(k0 + br) * N + bc4);
        const float4 b1 = *(const float4*)(Bb + (size_t)(k0 + br + 8) * N + bc4);
        __syncthreads();
        As[ac4 + 0][ar] = a0.x; As[ac4 + 1][ar] = a0.y;
        As[ac4 + 2][ar] = a0.z; As[ac4 + 3][ar] = a0.w;
        As[ac4 + 0][ar + 64] = a1.x; As[ac4 + 1][ar + 64] = a1.y;
        As[ac4 + 2][ar + 64] = a1.z; As[ac4 + 3][ar + 64] = a1.w;
        *(float4*)&Bs[br][bc4]     = b0;
        *(float4*)&Bs[br + 8][bc4] = b1;
        __syncthreads();
#pragma unroll
        for (int k = 0; k < BK; ++k) {
            float a[8], b[8];
            *(float4*)&a[0] = *(const float4*)&As[k][tr * 8];
            *(float4*)&a[4] = *(const float4*)&As[k][tr * 8 + 4];
            *(float4*)&b[0] = *(const float4*)&Bs[k][tc * 8];
            *(float4*)&b[4] = *(const float4*)&Bs[k][tc * 8 + 4];
#pragma unroll
            for (int i = 0; i < 8; ++i)
#pragma unroll
                for (int j = 0; j < 8; ++j)
                    acc[i][j] = fmaf(a[i], b[j], acc[i][j]);
        }
    }
    float bv[8];
#pragma unroll
    for (int j = 0; j < 8; ++j)
        bv[j] = HAS_BIAS ? bias[bx * BN + tc * 8 + j] : 0.f;
#pragma unroll
    for (int i = 0; i < 8; ++i) {
        const size_t row = (size_t)by * BM + tr * 8 + i;
        float o[8];
#pragma unroll
        for (int j = 0; j < 8; ++j) {
            float v = alpha * acc[i][j] + bv[j];
            if (RELU) v = fmaxf(v, 0.f);
            o[j] = v;
        }
        *(float4*)(C + row * N + bx * BN + tc * 8)     = *(const float4*)&o[0];
        *(float4*)(C + row * N + bx * BN + tc * 8 + 4) = *(const float4*)&o[4];
    }
}

// ---------------------------------------------- scoring GEMM (keys @ W_vs)
// Same tile as gemm_k; epilogue reduces each 32-col slot to a cosine score.
__global__ __launch_bounds__(256)
void score_gemm_k(const float* __restrict__ A /*keys [kN,kD]*/,
                  const float* __restrict__ B /*W_vs [kD, kSL*kOUT]*/,
                  const float* __restrict__ bias /*b_vs*/,
                  const float* __restrict__ X /*[kN,kOUT]*/,
                  const float* __restrict__ XN /*[kN]*/,
                  float* __restrict__ SC /*[kN,kSL]*/)
{
    constexpr int BM = 128, BN = 128, BK = 16;
    constexpr int K = kD, N = kSL * kOUT;
    __shared__ float As[BK][BM + 4];
    __shared__ float Bs[BK][BN];
    __shared__ float xs[BM][kOUT];
    __shared__ float xns[BM];
    const int tid = threadIdx.x;
    const int tr = tid >> 4, tc = tid & 15;
    const int bx = blockIdx.x, by = blockIdx.y;
    const int row0 = by * BM;
    const float* Ab = A + (size_t)by * BM * K;
    const float* Bb = B + (size_t)bx * BN;
    const int ar  = tid >> 2;
    const int ac4 = (tid & 3) << 2;
    const int br  = tid >> 5;
    const int bc4 = (tid & 31) << 2;

    // preload x tile + xnorm tile (synced by first barrier in k-loop)
#pragma unroll
    for (int it = 0; it < 4; ++it) {
        const int lin = it * 256 + tid;       // float4 index, 1024 total
        const int r = lin >> 3;
        const int c4 = (lin & 7) << 2;
        *(float4*)&xs[r][c4] = *(const float4*)(X + (size_t)(row0 + r) * kOUT + c4);
    }
    if (tid < BM) xns[tid] = XN[row0 + tid];

    float acc[8][8];
#pragma unroll
    for (int i = 0; i < 8; ++i)
#pragma unroll
        for (int j = 0; j < 8; ++j) acc[i][j] = 0.f;

    for (int k0 = 0; k0 < K; k0 += BK) {
        const float4 a0 = *(const float4*)(Ab + (size_t)ar * K + k0 + ac4);
        const float4 a1 = *(const float4*)(Ab + (size_t)(ar + 64) * K + k0 + ac4);
        const float4 b0 = *(const float4*)(Bb + (size_t)(k0 + br) * N + bc4);
        const float4 b1 = *(const float4*)(Bb + (size_t)(k0 + br + 8) * N + bc4);
        __syncthreads();
        As[ac4 + 0][ar] = a0.x; As[ac4 + 1][ar] = a0.y;
        As[ac4 + 2][ar] = a0.z; As[ac4 + 3][ar] = a0.w;
        As[ac4 + 0][ar + 64] = a1.x; As[ac4 + 1][ar + 64] = a1.y;
        As[ac4 + 2][ar + 64] = a1.z; As[ac4 + 3][ar + 64] = a1.w;
        *(float4*)&Bs[br][bc4]     = b0;
        *(float4*)&Bs[br + 8][bc4] = b1;
        __syncthreads();
#pragma unroll
        for (int k = 0; k < BK; ++k) {
            float a[8], b[8];
            *(float4*)&a[0] = *(const float4*)&As[k][tr * 8];
            *(float4*)&a[4] = *(const float4*)&As[k][tr * 8 + 4];
            *(float4*)&b[0] = *(const float4*)&Bs[k][tc * 8];
            *(float4*)&b[4] = *(const float4*)&Bs[k][tc * 8 + 4];
#pragma unroll
            for (int i = 0; i < 8; ++i)
#pragma unroll
                for (int j = 0; j < 8; ++j)
                    acc[i][j] = fmaf(a[i], b[j], acc[i][j]);
        }
    }
    // epilogue: 8 cols per thread lie inside one 32-col slot.
    const int slot_l = tc >> 2;           // local slot 0..3
    const int ob = (tc & 3) << 3;         // o offset within slot: 0,8,16,24
    const int colg = bx * BN + tc * 8;
    float bv[8];
#pragma unroll
    for (int j = 0; j < 8; ++j) bv[j] = bias[colg + j];
#pragma unroll
    for (int i = 0; i < 8; ++i) {
        const int lrow = tr * 8 + i;
        float pd = 0.f, pn = 0.f;
#pragma unroll
        for (int j = 0; j < 8; ++j) {
            const float v = acc[i][j] + bv[j];
            pd = fmaf(v, xs[lrow][ob + j], pd);
            pn = fmaf(v, v, pn);
        }
        pd += __shfl_xor(pd, 1); pd += __shfl_xor(pd, 2);
        pn += __shfl_xor(pn, 1); pn += __shfl_xor(pn, 2);
        if ((tc & 3) == 0) {
            const float score = pd / (sqrtf(pn) * xns[lrow]);
            SC[(size_t)(row0 + lrow) * kSL + bx * 4 + slot_l] = score;
        }
    }
}

// ----------------------------------------------- causal flash attention
// Q,K,V: [kN, kD] with cols h*64+e. One block = (b, h, 64 query rows).
__global__ __launch_bounds__(256)
void attn_k(const float* __restrict__ Q, const float* __restrict__ K,
            const float* __restrict__ V, float* __restrict__ O)
{
    __shared__ float Qs[64][68];   // [e][r]
    __shared__ float Ks[64][68];   // [e][c]
    __shared__ float Vs[64][68];   // [c][e]
    __shared__ float Ps[64][68];   // [r][c]
    const int tid = threadIdx.x;
    const int tr = tid >> 4, tc = tid & 15;
    const int qt = blockIdx.x & 15;
    const int h  = (blockIdx.x >> 4) & 7;
    const int b  = blockIdx.x >> 7;
    const int q0 = qt * 64;
    const float* Qb = Q + ((size_t)(b * kS + q0)) * kD + h * kHD;
    {
        const int r = tid >> 2;
#pragma unroll
        for (int it = 0; it < 4; ++it) {
            const int e0 = ((tid & 3) << 2) + it * 16;
            const float4 q4 = *(const float4*)(Qb + (size_t)r * kD + e0);
            Qs[e0 + 0][r] = q4.x; Qs[e0 + 1][r] = q4.y;
            Qs[e0 + 2][r] = q4.z; Qs[e0 + 3][r] = q4.w;
        }
    }
    float m[4], l[4], acc[4][4];
#pragma unroll
    for (int i = 0; i < 4; ++i) {
        m[i] = -INFINITY; l[i] = 0.f;
#pragma unroll
        for (int j = 0; j < 4; ++j) acc[i][j] = 0.f;
    }
    for (int j0 = 0; j0 <= q0; j0 += 64) {
        const float* Kb = K + ((size_t)(b * kS + j0)) * kD + h * kHD;
        const float* Vb = V + ((size_t)(b * kS + j0)) * kD + h * kHD;
        __syncthreads();
        {
            const int c = tid >> 2;
#pragma unroll
            for (int it = 0; it < 4; ++it) {
                const int e0 = ((tid & 3) << 2) + it * 16;
                const float4 k4 = *(const float4*)(Kb + (size_t)c * kD + e0);
                Ks[e0 + 0][c] = k4.x; Ks[e0 + 1][c] = k4.y;
                Ks[e0 + 2][c] = k4.z; Ks[e0 + 3][c] = k4.w;
                *(float4*)&Vs[c][e0] = *(const float4*)(Vb + (size_t)c * kD + e0);
            }
        }
        __syncthreads();
        float s[4][4];
#pragma unroll
        for (int i = 0; i < 4; ++i)
#pragma unroll
            for (int j = 0; j < 4; ++j) s[i][j] = 0.f;
        for (int e = 0; e < 64; ++e) {
            float qa[4], kb[4];
            *(float4*)&qa[0] = *(const float4*)&Qs[e][tr * 4];
            *(float4*)&kb[0] = *(const float4*)&Ks[e][tc * 4];
#pragma unroll
            for (int i = 0; i < 4; ++i)
#pragma unroll
                for (int j = 0; j < 4; ++j)
                    s[i][j] = fmaf(qa[i], kb[j], s[i][j]);
        }
        if (j0 == q0) {  // diagonal tile: causal mask
#pragma unroll
            for (int i = 0; i < 4; ++i)
#pragma unroll
                for (int j = 0; j < 4; ++j)
                    if (tc * 4 + j > tr * 4 + i) s[i][j] = -INFINITY;
        }
#pragma unroll
        for (int i = 0; i < 4; ++i) {
            float rm = fmaxf(fmaxf(s[i][0], s[i][1]), fmaxf(s[i][2], s[i][3]));
            rm = fmaxf(rm, __shfl_xor(rm, 1));
            rm = fmaxf(rm, __shfl_xor(rm, 2));
            rm = fmaxf(rm, __shfl_xor(rm, 4));
            rm = fmaxf(rm, __shfl_xor(rm, 8));
            const float mn = fmaxf(m[i], rm);
            const float co = expf(m[i] - mn);
            float ps = 0.f;
#pragma unroll
            for (int j = 0; j < 4; ++j) { s[i][j] = expf(s[i][j] - mn); ps += s[i][j]; }
            ps += __shfl_xor(ps, 1); ps += __shfl_xor(ps, 2);
            ps += __shfl_xor(ps, 4); ps += __shfl_xor(ps, 8);
            l[i] = l[i] * co + ps;
            m[i] = mn;
#pragma unroll
            for (int j = 0; j < 4; ++j) acc[i][j] *= co;
            *(float4*)&Ps[tr * 4 + i][tc * 4] = make_float4(s[i][0], s[i][1], s[i][2], s[i][3]);
        }
        __syncthreads();
        for (int c = 0; c < 64; ++c) {
            const float4 v4 = *(const float4*)&Vs[c][tc * 4];
#pragma unroll
            for (int i = 0; i < 4; ++i) {
                const float p = Ps[tr * 4 + i][c];
                acc[i][0] = fmaf(p, v4.x, acc[i][0]);
                acc[i][1] = fmaf(p, v4.y, acc[i][1]);
                acc[i][2] = fmaf(p, v4.z, acc[i][2]);
                acc[i][3] = fmaf(p, v4.w, acc[i][3]);
            }
        }
    }
    float* Ob = O + ((size_t)(b * kS + q0)) * kD + h * kHD;
#pragma unroll
    for (int i = 0; i < 4; ++i) {
        const float inv = 1.0f / l[i];
        *(float4*)(Ob + (size_t)(tr * 4 + i) * kD + tc * 4) =
            make_float4(acc[i][0] * inv, acc[i][1] * inv, acc[i][2] * inv, acc[i][3] * inv);
    }
}

// ---------------------------------------------------------- LayerNorm
// out = LN(a + b) * scale + bias ; b may be null. One wave per row of 512.
__global__ __launch_bounds__(256)
void ln_k(const float* __restrict__ a, const float* __restrict__ b,
          const float* __restrict__ sc, const float* __restrict__ bi,
          float* __restrict__ out)
{
    const int w = threadIdx.x >> 6, lane = threadIdx.x & 63;
    const size_t row = (size_t)blockIdx.x * 4 + w;
    const float* ap = a + row * kD;
    float x[8];
    *(float4*)&x[0] = *(const float4*)(ap + lane * 8);
    *(float4*)&x[4] = *(const float4*)(ap + lane * 8 + 4);
    if (b) {
        const float* bp = b + row * kD;
        float y[8];
        *(float4*)&y[0] = *(const float4*)(bp + lane * 8);
        *(float4*)&y[4] = *(const float4*)(bp + lane * 8 + 4);
#pragma unroll
        for (int k = 0; k < 8; ++k) x[k] += y[k];
    }
    float s = 0.f;
#pragma unroll
    for (int k = 0; k < 8; ++k) s += x[k];
    for (int msk = 1; msk < 64; msk <<= 1) s += __shfl_xor(s, msk);
    const float mean = s * (1.0f / 512.0f);
    float v = 0.f;
#pragma unroll
    for (int k = 0; k < 8; ++k) { const float d = x[k] - mean; v = fmaf(d, d, v); }
    for (int msk = 1; msk < 64; msk <<= 1) v += __shfl_xor(v, msk);
    const float rstd = 1.0f / sqrtf(v * (1.0f / 512.0f) + 1e-6f);
    float o[8];
#pragma unroll
    for (int k = 0; k < 8; ++k) {
        const int col = lane * 8 + k;
        o[k] = (x[k] - mean) * rstd * sc[col] + bi[col];
    }
    *(float4*)(out + row * kD + lane * 8)     = *(const float4*)&o[0];
    *(float4*)(out + row * kD + lane * 8 + 4) = *(const float4*)&o[4];
}

// ---------------------------------------------------------- row softmax
__global__ __launch_bounds__(256)
void softmax_k(const float* __restrict__ in, float* __restrict__ out)
{
    const int w = threadIdx.x >> 6, lane = threadIdx.x & 63;
    const size_t row = (size_t)blockIdx.x * 4 + w;
    const float* ip = in + row * kD;
    float x[8];
    *(float4*)&x[0] = *(const float4*)(ip + lane * 8);
    *(float4*)&x[4] = *(const float4*)(ip + lane * 8 + 4);
    float mx = x[0];
#pragma unroll
    for (int k = 1; k < 8; ++k) mx = fmaxf(mx, x[k]);
    for (int msk = 1; msk < 64; msk <<= 1) mx = fmaxf(mx, __shfl_xor(mx, msk));
    float s = 0.f;
#pragma unroll
    for (int k = 0; k < 8; ++k) { x[k] = expf(x[k] - mx); s += x[k]; }
    for (int msk = 1; msk < 64; msk <<= 1) s += __shfl_xor(s, msk);
    const float inv = 1.0f / s;
#pragma unroll
    for (int k = 0; k < 8; ++k) x[k] *= inv;
    *(float4*)(out + row * kD + lane * 8)     = *(const float4*)&x[0];
    *(float4*)(out + row * kD + lane * 8 + 4) = *(const float4*)&x[4];
}

// ---------------------------------------------------------- ||x_row||
__global__ __launch_bounds__(256)
void xnorm_k(const float* __restrict__ X, float* __restrict__ XN)
{
    const int tid = threadIdx.x;
    const int row = blockIdx.x * 8 + (tid >> 5);
    const int o = tid & 31;
    const float v = X[(size_t)row * kOUT + o];
    float s = v * v;
    s += __shfl_xor(s, 1); s += __shfl_xor(s, 2); s += __shfl_xor(s, 4);
    s += __shfl_xor(s, 8); s += __shfl_xor(s, 16);
    if (o == 0) XN[row] = sqrtf(s);
}

// ------------------------------------- argmax + gather winning slot column
__global__ __launch_bounds__(256)
void pick_k(const float* __restrict__ scores, const float* __restrict__ keys,
            const float* __restrict__ Wvs, const float* __restrict__ bvs,
            const float* __restrict__ Ss, float* __restrict__ vout,
            float* __restrict__ sout)
{
    const int n = blockIdx.x;
    const int tid = threadIdx.x;
    __shared__ float sv[256];
    __shared__ int   si[256];
    __shared__ float ks[512];
    __shared__ float red[256];
    const float s0 = scores[(size_t)n * kSL + tid];
    const float s1 = scores[(size_t)n * kSL + tid + 256];
    float bs; int bi;
    if (s1 > s0) { bs = s1; bi = tid + 256; } else { bs = s0; bi = tid; }
    sv[tid] = bs; si[tid] = bi;
    ks[tid] = keys[(size_t)n * kD + tid];
    ks[tid + 256] = keys[(size_t)n * kD + tid + 256];
    __syncthreads();
    for (int off = 128; off > 0; off >>= 1) {
        if (tid < off) {
            const float ov = sv[tid + off]; const int oi = si[tid + off];
            if (ov > sv[tid] || (ov == sv[tid] && oi < si[tid])) { sv[tid] = ov; si[tid] = oi; }
        }
        __syncthreads();
    }
    const int idx = si[0];
    // recompute winning column in fp32: v_out = keys[n] @ Wvs[:, idx*32 .. +32] + bvs
    const int o = tid & 31;
    const int seg = tid >> 5;            // 8 segments of 64
    const float* Wc = Wvs + (size_t)idx * kOUT + o;
    float part = 0.f;
    for (int d = seg * 64; d < seg * 64 + 64; ++d)
        part = fmaf(ks[d], Wc[(size_t)d * (kSL * kOUT)], part);
    red[tid] = part;
    __syncthreads();
    if (tid < 32) {
        float t = red[tid];
#pragma unroll
        for (int ss = 1; ss < 8; ++ss) t += red[tid + 32 * ss];
        vout[(size_t)n * kOUT + tid] = t + bvs[idx * kOUT + tid];
    }
    if (tid == 0) sout[n] = Ss[(size_t)n * kSL + idx];
}

// ------------------------------------------------------------------ host
extern "C" void kernel_launch(void* const* d_in, const int* in_sizes, int n_in,
                              void* d_out, int out_size, void* d_ws, size_t ws_size,
                              hipStream_t stream)
{
    (void)in_sizes; (void)n_in; (void)out_size; (void)ws_size;
    const float* s_in = (const float*)d_in[0];
    const float* x_in = (const float*)d_in[1];
    const float* t_in = (const float*)d_in[2];
    const float* Wq   = (const float*)d_in[3];
    const float* Wk   = (const float*)d_in[4];
    const float* Wv   = (const float*)d_in[5];
    const float* Wo   = (const float*)d_in[6];
    // d_in[7] cWq, d_in[8] cWk: unused — eye-mask cross-attn collapses to V path
    const float* cWv  = (const float*)d_in[9];
    const float* cWo  = (const float*)d_in[10];
    const float* ln1s = (const float*)d_in[11];
    const float* ln1b = (const float*)d_in[12];
    const float* ln2s = (const float*)d_in[13];
    const float* ln2b = (const float*)d_in[14];
    const float* ln3s = (const float*)d_in[15];
    const float* ln3b = (const float*)d_in[16];
    const float* W1   = (const float*)d_in[17];
    const float* b1   = (const float*)d_in[18];
    const float* W2   = (const float*)d_in[19];
    const float* b2   = (const float*)d_in[20];
    const float* lnfs = (const float*)d_in[21];
    const float* lnfb = (const float*)d_in[22];
    const float* Wout = (const float*)d_in[23];
    const float* bout = (const float*)d_in[24];
    const float* Wvs  = (const float*)d_in[25];
    const float* bvs  = (const float*)d_in[26];
    const float* Wss  = (const float*)d_in[27];
    const float* bss  = (const float*)d_in[28];

    float* out_v  = (float*)d_out;                       // [kN, kOUT]
    float* out_s  = out_v + (size_t)kN * kOUT;           // [kN]
    float* out_Ss = out_s + kN;                          // [kN, kSL]

    float* ws    = (float*)d_ws;
    float* f_dec = ws;
    float* f_A   = f_dec + (size_t)kN * kD;
    float* f_B   = f_A + (size_t)kN * kD;
    float* f_C   = f_B + (size_t)kN * kD;
    float* f_D   = f_C + (size_t)kN * kD;
    float* f_hid = f_D + (size_t)kN * kD;                // [kN, kFF]
    float* f_xn  = f_hid + (size_t)kN * kFF;             // [kN]
    float* f_sc  = f_hid;                                // reuse hid for scores

    const dim3 blk(256);
    const dim3 g512(kD / 128, kN / 128);
    const dim3 gff(kFF / 128, kN / 128);

    xnorm_k<<<kN / 8, blk, 0, stream>>>(x_in, f_xn);

    const float* cur = s_in;
    for (int l = 0; l < 2; ++l) {
        const size_t w_off = (size_t)l * kD * kD;
        // self-attention (q pre-scaled by 1/sqrt(64))
        gemm_k<0, 0><<<g512, blk, 0, stream>>>(cur, Wq + w_off, nullptr, f_A, kN, kD, kD, 0.125f);
        gemm_k<0, 0><<<g512, blk, 0, stream>>>(cur, Wk + w_off, nullptr, f_B, kN, kD, kD, 1.f);
        gemm_k<0, 0><<<g512, blk, 0, stream>>>(cur, Wv + w_off, nullptr, f_C, kN, kD, kD, 1.f);
        attn_k<<<1024, blk, 0, stream>>>(f_A, f_B, f_C, f_D);
        gemm_k<0, 0><<<g512, blk, 0, stream>>>(f_D, Wo + w_off, nullptr, f_A, kN, kD, kD, 1.f);
        ln_k<<<kN / 4, blk, 0, stream>>>(cur, f_A, ln1s + l * kD, ln1b + l * kD, f_dec);
        // cross-attention == (t @ cWv) @ cWo
        gemm_k<0, 0><<<g512, blk, 0, stream>>>(t_in, cWv + w_off, nullptr, f_A, kN, kD, kD, 1.f);
        gemm_k<0, 0><<<g512, blk, 0, stream>>>(f_A, cWo + w_off, nullptr, f_D, kN, kD, kD, 1.f);
        ln_k<<<kN / 4, blk, 0, stream>>>(f_dec, f_D, ln2s + l * kD, ln2b + l * kD, f_dec);
        // FFN
        gemm_k<1, 1><<<gff, blk, 0, stream>>>(f_dec, W1 + (size_t)l * kD * kFF, b1 + (size_t)l * kFF,
                                              f_hid, kN, kFF, kD, 1.f);
        gemm_k<0, 1><<<g512, blk, 0, stream>>>(f_hid, W2 + (size_t)l * kFF * kD, b2 + (size_t)l * kD,
                                               f_A, kN, kD, kFF, 1.f);
        ln_k<<<kN / 4, blk, 0, stream>>>(f_dec, f_A, ln3s + l * kD, ln3b + l * kD, f_dec);
        cur = f_dec;
    }
    // final LN -> logits -> keys
    ln_k<<<kN / 4, blk, 0, stream>>>(f_dec, nullptr, lnfs, lnfb, f_A);
    gemm_k<0, 1><<<g512, blk, 0, stream>>>(f_A, Wout, bout, f_D, kN, kD, kD, 1.f);
    softmax_k<<<kN / 4, blk, 0, stream>>>(f_D, f_A);     // keys in f_A
    // Ss straight into d_out
    gemm_k<0, 1><<<g512, blk, 0, stream>>>(f_A, Wss, bss, out_Ss, kN, kSL, kD, 1.f);
    // fused cosine scoring (Vs never materialized)
    score_gemm_k<<<dim3(kSL * kOUT / 128, kN / 128), blk, 0, stream>>>(f_A, Wvs, bvs, x_in, f_xn, f_sc);
    // argmax + winning-column gather
    pick_k<<<kN, blk, 0, stream>>>(f_sc, f_A, Wvs, bvs, out_Ss, out_v, out_s);
}

// Round 2
// 2189.587 us; speedup vs baseline: 2.0372x; 2.0372x over previous
//
#include <hip/hip_runtime.h>
#include <math.h>

namespace {
constexpr int kD   = 512;
constexpr int kN   = 8192;
constexpr int kS   = 1024;
constexpr int kHD  = 64;
constexpr int kFF  = 2048;
constexpr int kSL  = 512;
constexpr int kOUT = 32;
}

typedef __bf16 bf16x8 __attribute__((ext_vector_type(8)));
typedef float  f32x4  __attribute__((ext_vector_type(4)));

__device__ inline unsigned short f2bf(float x) {
    unsigned u = __float_as_uint(x);
    return (unsigned short)((u + 0x7FFF + ((u >> 16) & 1)) >> 16);
}
__device__ inline void split2(float x, unsigned short& h, unsigned short& l) {
    unsigned u = __float_as_uint(x);
    unsigned hb = (u + 0x7FFF + ((u >> 16) & 1)) >> 16;
    h = (unsigned short)hb;
    float hf = __uint_as_float(hb << 16);
    l = f2bf(x - hf);
}

// =====================================================================
// Split-precision MFMA GEMM.
// A planes: [M][K] bf16 (hi,lo).  B planes: [N][K] bf16 (B^T, hi,lo).
// MODE 0: C fp32 [M][N] (+bias, relu, alpha)
// MODE 1: C -> hi/lo bf16 planes (+bias, relu)
// MODE 2: fused cosine-score epilogue -> SC [M][N/32]
// Block 128x128, 4 waves (64x64 each), BK=64, XOR-swizzled LDS.
// =====================================================================
template<int MODE, int RELU, int HAS_BIAS>
__global__ __launch_bounds__(256)
void mgemm_k(const unsigned short* __restrict__ Ah, const unsigned short* __restrict__ Al,
             const unsigned short* __restrict__ Bh, const unsigned short* __restrict__ Bl,
             const float* __restrict__ bias, float* __restrict__ C,
             unsigned short* __restrict__ Ch, unsigned short* __restrict__ Cl,
             const float* __restrict__ X, const float* __restrict__ XN,
             float* __restrict__ SC,
             int M, int N, int K, float alpha)
{
    __shared__ uint4 smem_u4[4096];                 // 64 KB: Ah|Al|Bh|Bl, 16 KB each
    unsigned char* smem = (unsigned char*)smem_u4;
    const int tid  = threadIdx.x;
    const int lane = tid & 63;
    const int w    = tid >> 6;
    const int brow = blockIdx.y * 128;
    const int bcol = blockIdx.x * 128;
    const int wr = (w >> 1) * 64, wc = (w & 1) * 64;
    const size_t Kb = (size_t)K * 2;

    // staging: wave w owns plane w (0:Ah 1:Al 2:Bh 3:Bl); 16 issues x 1KB
    const unsigned short* srcM; int rb;
    if      (w == 0) { srcM = Ah; rb = brow; }
    else if (w == 1) { srcM = Al; rb = brow; }
    else if (w == 2) { srcM = Bh; rb = bcol; }
    else             { srcM = Bl; rb = bcol; }
    const int swzsrc = (((lane & 7) << 4) ^ (((lane >> 3) & 7) << 4));
    const unsigned char* srow = (const unsigned char*)srcM
                              + (size_t)(rb + (lane >> 3)) * Kb + swzsrc;
    unsigned char* dbase = smem + w * 16384;

    const int lm = lane & 15;     // row within fragment
    const int lg = lane >> 4;     // k-group 0..3
    const int lswz = (lane & 7);  // row&7 for swizzle

    f32x4 acc[4][4];
#pragma unroll
    for (int i = 0; i < 4; ++i)
#pragma unroll
        for (int j = 0; j < 4; ++j) acc[i][j] = (f32x4)(0.f);

    for (int k0 = 0; k0 < K; k0 += 64) {
#pragma unroll
        for (int j = 0; j < 16; ++j) {
            const unsigned char* sp = srow + (size_t)(j * 8) * Kb + (size_t)k0 * 2;
            __builtin_amdgcn_global_load_lds(
                (const __attribute__((address_space(1))) unsigned int*)sp,
                (__attribute__((address_space(3))) unsigned int*)(dbase + j * 1024),
                16, 0, 0);
        }
        __syncthreads();
#pragma unroll
        for (int ks = 0; ks < 2; ++ks) {
            const int kf = (((ks << 2) + lg) ^ lswz) << 4;
            bf16x8 bh[4], bl[4];
#pragma unroll
            for (int n = 0; n < 4; ++n) {
                const int r = wc + n * 16 + lm;
                bh[n] = *(const bf16x8*)(smem + 32768 + r * 128 + kf);
                bl[n] = *(const bf16x8*)(smem + 49152 + r * 128 + kf);
            }
#pragma unroll
            for (int m = 0; m < 4; ++m) {
                const int r = wr + m * 16 + lm;
                bf16x8 ah = *(const bf16x8*)(smem +         r * 128 + kf);
                bf16x8 al = *(const bf16x8*)(smem + 16384 + r * 128 + kf);
#pragma unroll
                for (int n = 0; n < 4; ++n) {
                    acc[m][n] = __builtin_amdgcn_mfma_f32_16x16x32_bf16(al, bh[n], acc[m][n], 0, 0, 0);
                    acc[m][n] = __builtin_amdgcn_mfma_f32_16x16x32_bf16(ah, bl[n], acc[m][n], 0, 0, 0);
                    acc[m][n] = __builtin_amdgcn_mfma_f32_16x16x32_bf16(ah, bh[n], acc[m][n], 0, 0, 0);
                }
            }
        }
        __syncthreads();
    }

    if (MODE == 0 || MODE == 1) {
#pragma unroll
        for (int n = 0; n < 4; ++n) {
            const int colg = bcol + wc + n * 16 + lm;
            const float bv = HAS_BIAS ? bias[colg] : 0.f;
#pragma unroll
            for (int m = 0; m < 4; ++m) {
                const int rowb = brow + wr + m * 16 + lg * 4;
#pragma unroll
                for (int r = 0; r < 4; ++r) {
                    float v = alpha * acc[m][n][r] + bv;
                    if (RELU) v = fmaxf(v, 0.f);
                    if (MODE == 0) {
                        C[(size_t)(rowb + r) * N + colg] = v;
                    } else {
                        unsigned short h, l;
                        split2(v, h, l);
                        Ch[(size_t)(rowb + r) * N + colg] = h;
                        Cl[(size_t)(rowb + r) * N + colg] = l;
                    }
                }
            }
        }
    } else {
        // cosine-score epilogue: wave cols = 2 slots of 32
        float bv[4];
#pragma unroll
        for (int n = 0; n < 4; ++n) bv[n] = bias[bcol + wc + n * 16 + lm];
        const int slot0 = (bcol + wc) >> 5;
#pragma unroll
        for (int m = 0; m < 4; ++m) {
#pragma unroll
            for (int r = 0; r < 4; ++r) {
                const int row = brow + wr + m * 16 + lg * 4 + r;
                const float x0 = X[(size_t)row * kOUT + lm];
                const float x1 = X[(size_t)row * kOUT + 16 + lm];
                const float xn = XN[row];
#pragma unroll
                for (int s = 0; s < 2; ++s) {
                    const float v0 = acc[m][2 * s][r]     + bv[2 * s];
                    const float v1 = acc[m][2 * s + 1][r] + bv[2 * s + 1];
                    float pd = v0 * x0 + v1 * x1;
                    float pn = v0 * v0 + v1 * v1;
                    pd += __shfl_xor(pd, 1); pd += __shfl_xor(pd, 2);
                    pd += __shfl_xor(pd, 4); pd += __shfl_xor(pd, 8);
                    pn += __shfl_xor(pn, 1); pn += __shfl_xor(pn, 2);
                    pn += __shfl_xor(pn, 4); pn += __shfl_xor(pn, 8);
                    if (lm == 0)
                        SC[(size_t)row * kSL + slot0 + s] = pd / (sqrtf(pn) * xn);
                }
            }
        }
    }
}

// ---------------------------------------------- weight transpose + split
// W [K][N] fp32 -> TH/TL [N][K] bf16
__global__ __launch_bounds__(256)
void tsplit_k(const float* __restrict__ W, unsigned short* __restrict__ TH,
              unsigned short* __restrict__ TL, int K, int N)
{
    __shared__ float t[32][33];
    const int tid = threadIdx.x;
    const int n0 = blockIdx.x * 32, k0 = blockIdx.y * 32;
    {
        const int r = tid >> 3, c = (tid & 7) * 4;
        const float4 v = *(const float4*)(W + (size_t)(k0 + r) * N + n0 + c);
        t[r][c] = v.x; t[r][c + 1] = v.y; t[r][c + 2] = v.z; t[r][c + 3] = v.w;
    }
    __syncthreads();
    const int rn = tid >> 3, ck = (tid & 7) * 4;
    unsigned short h[4], l[4];
#pragma unroll
    for (int i = 0; i < 4; ++i) split2(t[ck + i][rn], h[i], l[i]);
    *(ushort4*)(TH + (size_t)(n0 + rn) * K + k0 + ck) = make_ushort4(h[0], h[1], h[2], h[3]);
    *(ushort4*)(TL + (size_t)(n0 + rn) * K + k0 + ck) = make_ushort4(l[0], l[1], l[2], l[3]);
}

// ---------------------------------------------------------- split fp32 -> planes
__global__ __launch_bounds__(256)
void split_k(const float* __restrict__ in, unsigned short* __restrict__ hi,
             unsigned short* __restrict__ lo, int n4)
{
    int i = blockIdx.x * 256 + threadIdx.x;
    const int stride = gridDim.x * 256;
    for (; i < n4; i += stride) {
        const float4 v = *(const float4*)(in + (size_t)i * 4);
        unsigned short h[4], l[4];
        split2(v.x, h[0], l[0]); split2(v.y, h[1], l[1]);
        split2(v.z, h[2], l[2]); split2(v.w, h[3], l[3]);
        *(ushort4*)(hi + (size_t)i * 4) = make_ushort4(h[0], h[1], h[2], h[3]);
        *(ushort4*)(lo + (size_t)i * 4) = make_ushort4(l[0], l[1], l[2], l[3]);
    }
}

// ----------------------------------------------- causal flash attention (fp32)
__global__ __launch_bounds__(256)
void attn_k(const float* __restrict__ Q, const float* __restrict__ K,
            const float* __restrict__ V, float* __restrict__ O)
{
    __shared__ float Qs[64][68];
    __shared__ float Ks[64][68];
    __shared__ float Vs[64][68];
    __shared__ float Ps[64][68];
    const int tid = threadIdx.x;
    const int tr = tid >> 4, tc = tid & 15;
    const int qt = blockIdx.x & 15;
    const int h  = (blockIdx.x >> 4) & 7;
    const int b  = blockIdx.x >> 7;
    const int q0 = qt * 64;
    const float* Qb = Q + ((size_t)(b * kS + q0)) * kD + h * kHD;
    {
        const int r = tid >> 2;
#pragma unroll
        for (int it = 0; it < 4; ++it) {
            const int e0 = ((tid & 3) << 2) + it * 16;
            const float4 q4 = *(const float4*)(Qb + (size_t)r * kD + e0);
            Qs[e0 + 0][r] = q4.x; Qs[e0 + 1][r] = q4.y;
            Qs[e0 + 2][r] = q4.z; Qs[e0 + 3][r] = q4.w;
        }
    }
    float m[4], l[4], acc[4][4];
#pragma unroll
    for (int i = 0; i < 4; ++i) {
        m[i] = -INFINITY; l[i] = 0.f;
#pragma unroll
        for (int j = 0; j < 4; ++j) acc[i][j] = 0.f;
    }
    for (int j0 = 0; j0 <= q0; j0 += 64) {
        const float* Kb = K + ((size_t)(b * kS + j0)) * kD + h * kHD;
        const float* Vb = V + ((size_t)(b * kS + j0)) * kD + h * kHD;
        __syncthreads();
        {
            const int c = tid >> 2;
#pragma unroll
            for (int it = 0; it < 4; ++it) {
                const int e0 = ((tid & 3) << 2) + it * 16;
                const float4 k4 = *(const float4*)(Kb + (size_t)c * kD + e0);
                Ks[e0 + 0][c] = k4.x; Ks[e0 + 1][c] = k4.y;
                Ks[e0 + 2][c] = k4.z; Ks[e0 + 3][c] = k4.w;
                *(float4*)&Vs[c][e0] = *(const float4*)(Vb + (size_t)c * kD + e0);
            }
        }
        __syncthreads();
        float s[4][4];
#pragma unroll
        for (int i = 0; i < 4; ++i)
#pragma unroll
            for (int j = 0; j < 4; ++j) s[i][j] = 0.f;
        for (int e = 0; e < 64; ++e) {
            float qa[4], kb[4];
            *(float4*)&qa[0] = *(const float4*)&Qs[e][tr * 4];
            *(float4*)&kb[0] = *(const float4*)&Ks[e][tc * 4];
#pragma unroll
            for (int i = 0; i < 4; ++i)
#pragma unroll
                for (int j = 0; j < 4; ++j)
                    s[i][j] = fmaf(qa[i], kb[j], s[i][j]);
        }
        if (j0 == q0) {
#pragma unroll
            for (int i = 0; i < 4; ++i)
#pragma unroll
                for (int j = 0; j < 4; ++j)
                    if (tc * 4 + j > tr * 4 + i) s[i][j] = -INFINITY;
        }
#pragma unroll
        for (int i = 0; i < 4; ++i) {
            float rm = fmaxf(fmaxf(s[i][0], s[i][1]), fmaxf(s[i][2], s[i][3]));
            rm = fmaxf(rm, __shfl_xor(rm, 1));
            rm = fmaxf(rm, __shfl_xor(rm, 2));
            rm = fmaxf(rm, __shfl_xor(rm, 4));
            rm = fmaxf(rm, __shfl_xor(rm, 8));
            const float mn = fmaxf(m[i], rm);
            const float co = expf(m[i] - mn);
            float ps = 0.f;
#pragma unroll
            for (int j = 0; j < 4; ++j) { s[i][j] = expf(s[i][j] - mn); ps += s[i][j]; }
            ps += __shfl_xor(ps, 1); ps += __shfl_xor(ps, 2);
            ps += __shfl_xor(ps, 4); ps += __shfl_xor(ps, 8);
            l[i] = l[i] * co + ps;
            m[i] = mn;
#pragma unroll
            for (int j = 0; j < 4; ++j) acc[i][j] *= co;
            *(float4*)&Ps[tr * 4 + i][tc * 4] = make_float4(s[i][0], s[i][1], s[i][2], s[i][3]);
        }
        __syncthreads();
        for (int c = 0; c < 64; ++c) {
            const float4 v4 = *(const float4*)&Vs[c][tc * 4];
#pragma unroll
            for (int i = 0; i < 4; ++i) {
                const float p = Ps[tr * 4 + i][c];
                acc[i][0] = fmaf(p, v4.x, acc[i][0]);
                acc[i][1] = fmaf(p, v4.y, acc[i][1]);
                acc[i][2] = fmaf(p, v4.z, acc[i][2]);
                acc[i][3] = fmaf(p, v4.w, acc[i][3]);
            }
        }
    }
    float* Ob = O + ((size_t)(b * kS + q0)) * kD + h * kHD;
#pragma unroll
    for (int i = 0; i < 4; ++i) {
        const float inv = 1.0f / l[i];
        *(float4*)(Ob + (size_t)(tr * 4 + i) * kD + tc * 4) =
            make_float4(acc[i][0] * inv, acc[i][1] * inv, acc[i][2] * inv, acc[i][3] * inv);
    }
}

// ---------------------------------------------------------- LayerNorm (+planes)
__global__ __launch_bounds__(256)
void ln_k(const float* __restrict__ a, const float* __restrict__ b,
          const float* __restrict__ sc, const float* __restrict__ bi,
          float* __restrict__ out, unsigned short* __restrict__ oh,
          unsigned short* __restrict__ ol)
{
    const int w = threadIdx.x >> 6, lane = threadIdx.x & 63;
    const size_t row = (size_t)blockIdx.x * 4 + w;
    const float* ap = a + row * kD;
    float x[8];
    *(float4*)&x[0] = *(const float4*)(ap + lane * 8);
    *(float4*)&x[4] = *(const float4*)(ap + lane * 8 + 4);
    if (b) {
        const float* bp = b + row * kD;
        float y[8];
        *(float4*)&y[0] = *(const float4*)(bp + lane * 8);
        *(float4*)&y[4] = *(const float4*)(bp + lane * 8 + 4);
#pragma unroll
        for (int k = 0; k < 8; ++k) x[k] += y[k];
    }
    float s = 0.f;
#pragma unroll
    for (int k = 0; k < 8; ++k) s += x[k];
    for (int msk = 1; msk < 64; msk <<= 1) s += __shfl_xor(s, msk);
    const float mean = s * (1.0f / 512.0f);
    float v = 0.f;
#pragma unroll
    for (int k = 0; k < 8; ++k) { const float d = x[k] - mean; v = fmaf(d, d, v); }
    for (int msk = 1; msk < 64; msk <<= 1) v += __shfl_xor(v, msk);
    const float rstd = 1.0f / sqrtf(v * (1.0f / 512.0f) + 1e-6f);
    float o[8]; unsigned short h[8], lo2[8];
#pragma unroll
    for (int k = 0; k < 8; ++k) {
        const int col = lane * 8 + k;
        o[k] = (x[k] - mean) * rstd * sc[col] + bi[col];
        split2(o[k], h[k], lo2[k]);
    }
    *(float4*)(out + row * kD + lane * 8)     = *(const float4*)&o[0];
    *(float4*)(out + row * kD + lane * 8 + 4) = *(const float4*)&o[4];
    *(ushort4*)(oh + row * kD + lane * 8)     = make_ushort4(h[0], h[1], h[2], h[3]);
    *(ushort4*)(oh + row * kD + lane * 8 + 4) = make_ushort4(h[4], h[5], h[6], h[7]);
    *(ushort4*)(ol + row * kD + lane * 8)     = make_ushort4(lo2[0], lo2[1], lo2[2], lo2[3]);
    *(ushort4*)(ol + row * kD + lane * 8 + 4) = make_ushort4(lo2[4], lo2[5], lo2[6], lo2[7]);
}

// ---------------------------------------------------------- row softmax (+planes)
__global__ __launch_bounds__(256)
void softmax_k(const float* __restrict__ in, float* __restrict__ out,
               unsigned short* __restrict__ oh, unsigned short* __restrict__ ol)
{
    const int w = threadIdx.x >> 6, lane = threadIdx.x & 63;
    const size_t row = (size_t)blockIdx.x * 4 + w;
    const float* ip = in + row * kD;
    float x[8];
    *(float4*)&x[0] = *(const float4*)(ip + lane * 8);
    *(float4*)&x[4] = *(const float4*)(ip + lane * 8 + 4);
    float mx = x[0];
#pragma unroll
    for (int k = 1; k < 8; ++k) mx = fmaxf(mx, x[k]);
    for (int msk = 1; msk < 64; msk <<= 1) mx = fmaxf(mx, __shfl_xor(mx, msk));
    float s = 0.f;
#pragma unroll
    for (int k = 0; k < 8; ++k) { x[k] = expf(x[k] - mx); s += x[k]; }
    for (int msk = 1; msk < 64; msk <<= 1) s += __shfl_xor(s, msk);
    const float inv = 1.0f / s;
    unsigned short h[8], lo2[8];
#pragma unroll
    for (int k = 0; k < 8; ++k) { x[k] *= inv; split2(x[k], h[k], lo2[k]); }
    *(float4*)(out + row * kD + lane * 8)     = *(const float4*)&x[0];
    *(float4*)(out + row * kD + lane * 8 + 4) = *(const float4*)&x[4];
    *(ushort4*)(oh + row * kD + lane * 8)     = make_ushort4(h[0], h[1], h[2], h[3]);
    *(ushort4*)(oh + row * kD + lane * 8 + 4) = make_ushort4(h[4], h[5], h[6], h[7]);
    *(ushort4*)(ol + row * kD + lane * 8)     = make_ushort4(lo2[0], lo2[1], lo2[2], lo2[3]);
    *(ushort4*)(ol + row * kD + lane * 8 + 4) = make_ushort4(lo2[4], lo2[5], lo2[6], lo2[7]);
}

// ---------------------------------------------------------- ||x_row||
__global__ __launch_bounds__(256)
void xnorm_k(const float* __restrict__ X, float* __restrict__ XN)
{
    const int tid = threadIdx.x;
    const int row = blockIdx.x * 8 + (tid >> 5);
    const int o = tid & 31;
    const float v = X[(size_t)row * kOUT + o];
    float s = v * v;
    s += __shfl_xor(s, 1); s += __shfl_xor(s, 2); s += __shfl_xor(s, 4);
    s += __shfl_xor(s, 8); s += __shfl_xor(s, 16);
    if (o == 0) XN[row] = sqrtf(s);
}

// ------------------------------------- argmax + gather winning slot column
__global__ __launch_bounds__(256)
void pick_k(const float* __restrict__ scores, const float* __restrict__ keys,
            const float* __restrict__ Wvs, const float* __restrict__ bvs,
            const float* __restrict__ Ss, float* __restrict__ vout,
            float* __restrict__ sout)
{
    const int n = blockIdx.x;
    const int tid = threadIdx.x;
    __shared__ float sv[256];
    __shared__ int   si[256];
    __shared__ float ks[512];
    __shared__ float red[256];
    const float s0 = scores[(size_t)n * kSL + tid];
    const float s1 = scores[(size_t)n * kSL + tid + 256];
    float bs; int bi;
    if (s1 > s0) { bs = s1; bi = tid + 256; } else { bs = s0; bi = tid; }
    sv[tid] = bs; si[tid] = bi;
    ks[tid] = keys[(size_t)n * kD + tid];
    ks[tid + 256] = keys[(size_t)n * kD + tid + 256];
    __syncthreads();
    for (int off = 128; off > 0; off >>= 1) {
        if (tid < off) {
            const float ov = sv[tid + off]; const int oi = si[tid + off];
            if (ov > sv[tid] || (ov == sv[tid] && oi < si[tid])) { sv[tid] = ov; si[tid] = oi; }
        }
        __syncthreads();
    }
    const int idx = si[0];
    const int o = tid & 31;
    const int seg = tid >> 5;
    const float* Wc = Wvs + (size_t)idx * kOUT + o;
    float part = 0.f;
    for (int d = seg * 64; d < seg * 64 + 64; ++d)
        part = fmaf(ks[d], Wc[(size_t)d * (kSL * kOUT)], part);
    red[tid] = part;
    __syncthreads();
    if (tid < 32) {
        float t = red[tid];
#pragma unroll
        for (int ss = 1; ss < 8; ++ss) t += red[tid + 32 * ss];
        vout[(size_t)n * kOUT + tid] = t + bvs[idx * kOUT + tid];
    }
    if (tid == 0) sout[n] = Ss[(size_t)n * kSL + idx];
}

// ------------------------------------------------------------------ host
extern "C" void kernel_launch(void* const* d_in, const int* in_sizes, int n_in,
                              void* d_out, int out_size, void* d_ws, size_t ws_size,
                              hipStream_t stream)
{
    (void)in_sizes; (void)n_in; (void)out_size; (void)ws_size;
    const float* s_in = (const float*)d_in[0];
    const float* x_in = (const float*)d_in[1];
    const float* t_in = (const float*)d_in[2];
    const float* Wq   = (const float*)d_in[3];
    const float* Wk   = (const float*)d_in[4];
    const float* Wv   = (const float*)d_in[5];
    const float* Wo   = (const float*)d_in[6];
    const float* cWv  = (const float*)d_in[9];
    const float* cWo  = (const float*)d_in[10];
    const float* ln1s = (const float*)d_in[11];
    const float* ln1b = (const float*)d_in[12];
    const float* ln2s = (const float*)d_in[13];
    const float* ln2b = (const float*)d_in[14];
    const float* ln3s = (const float*)d_in[15];
    const float* ln3b = (const float*)d_in[16];
    const float* W1   = (const float*)d_in[17];
    const float* b1   = (const float*)d_in[18];
    const float* W2   = (const float*)d_in[19];
    const float* b2   = (const float*)d_in[20];
    const float* lnfs = (const float*)d_in[21];
    const float* lnfb = (const float*)d_in[22];
    const float* Wout = (const float*)d_in[23];
    const float* bout = (const float*)d_in[24];
    const float* Wvs  = (const float*)d_in[25];
    const float* bvs  = (const float*)d_in[26];
    const float* Wss  = (const float*)d_in[27];
    const float* bss  = (const float*)d_in[28];

    float* out_v  = (float*)d_out;
    float* out_s  = out_v + (size_t)kN * kOUT;
    float* out_Ss = out_s + kN;

    // ---- workspace layout (~181 MB) ----
    unsigned char* w8 = (unsigned char*)d_ws;
    const size_t MD = (size_t)kN * kD;           // 4M elems
    float* f_dec = (float*)w8;                                    // 16 MB
    float* f_A   = f_dec + MD;                                    // 16 MB
    float* f_B   = f_A + MD;                                      // 16 MB
    float* f_C   = f_B + MD;                                      // 16 MB
    float* f_xn  = f_C + MD;                                      // 32 KB
    unsigned short* dH = (unsigned short*)(f_xn + kN);            // 8 MB
    unsigned short* dL = dH + MD;                                 // 8 MB
    unsigned short* hH = dL + MD;                                 // 33.5 MB  [kN][kFF]
    unsigned short* hL = hH + (size_t)kN * kFF;                   // 33.5 MB
    unsigned short* wTH = hL + (size_t)kN * kFF;                  // 16.8 MB  [<=16384][<=2048]
    unsigned short* wTL = wTH + (size_t)kSL * kOUT * kD;          // 16.8 MB
    unsigned short* sH = hH;            // alias: activation split (4M)
    unsigned short* sL = hL;
    unsigned short* kH = hH + MD;       // alias: keys planes (4M)
    unsigned short* kL = hL + MD;

    const dim3 blk(256);
    const size_t DD = (size_t)kD * kD;

    auto tsplit = [&](const float* W, int K, int N) {
        tsplit_k<<<dim3(N / 32, K / 32), blk, 0, stream>>>(W, wTH, wTL, K, N);
    };
    auto gemm = [&](const unsigned short* aH, const unsigned short* aL,
                    const float* bias, float* out, int N, int K, float alpha) {
        if (bias)
            mgemm_k<0, 0, 1><<<dim3(N / 128, kN / 128), blk, 0, stream>>>(
                aH, aL, wTH, wTL, bias, out, nullptr, nullptr, nullptr, nullptr, nullptr,
                kN, N, K, alpha);
        else
            mgemm_k<0, 0, 0><<<dim3(N / 128, kN / 128), blk, 0, stream>>>(
                aH, aL, wTH, wTL, nullptr, out, nullptr, nullptr, nullptr, nullptr, nullptr,
                kN, N, K, alpha);
    };

    xnorm_k<<<kN / 8, blk, 0, stream>>>(x_in, f_xn);
    split_k<<<1024, blk, 0, stream>>>(s_in, dH, dL, (int)(MD / 4));

    const float* cur = s_in;
    for (int l = 0; l < 2; ++l) {
        const size_t wo = (size_t)l * DD;
        // self-attention
        tsplit(Wq + wo, kD, kD); gemm(dH, dL, nullptr, f_A, kD, kD, 0.125f);
        tsplit(Wk + wo, kD, kD); gemm(dH, dL, nullptr, f_B, kD, kD, 1.f);
        tsplit(Wv + wo, kD, kD); gemm(dH, dL, nullptr, f_C, kD, kD, 1.f);
        attn_k<<<1024, blk, 0, stream>>>(f_A, f_B, f_C, f_A);
        split_k<<<1024, blk, 0, stream>>>(f_A, sH, sL, (int)(MD / 4));
        tsplit(Wo + wo, kD, kD); gemm(sH, sL, nullptr, f_B, kD, kD, 1.f);
        ln_k<<<kN / 4, blk, 0, stream>>>(cur, f_B, ln1s + l * kD, ln1b + l * kD, f_dec, dH, dL);
        // cross-attention (eye mask) == (t @ cWv) @ cWo
        split_k<<<1024, blk, 0, stream>>>(t_in, sH, sL, (int)(MD / 4));
        tsplit(cWv + wo, kD, kD); gemm(sH, sL, nullptr, f_A, kD, kD, 1.f);
        split_k<<<1024, blk, 0, stream>>>(f_A, sH, sL, (int)(MD / 4));
        tsplit(cWo + wo, kD, kD); gemm(sH, sL, nullptr, f_A, kD, kD, 1.f);
        ln_k<<<kN / 4, blk, 0, stream>>>(f_dec, f_A, ln2s + l * kD, ln2b + l * kD, f_dec, dH, dL);
        // FFN (hidden kept only as bf16 hi/lo planes)
        tsplit(W1 + (size_t)l * kD * kFF, kD, kFF);
        mgemm_k<1, 1, 1><<<dim3(kFF / 128, kN / 128), blk, 0, stream>>>(
            dH, dL, wTH, wTL, b1 + (size_t)l * kFF, nullptr, hH, hL,
            nullptr, nullptr, nullptr, kN, kFF, kD, 1.f);
        tsplit(W2 + (size_t)l * kFF * kD, kFF, kD);
        gemm(hH, hL, b2 + (size_t)l * kD, f_A, kD, kFF, 1.f);
        ln_k<<<kN / 4, blk, 0, stream>>>(f_dec, f_A, ln3s + l * kD, ln3b + l * kD, f_dec, dH, dL);
        cur = f_dec;
    }
    // final LN -> logits -> keys
    ln_k<<<kN / 4, blk, 0, stream>>>(f_dec, nullptr, lnfs, lnfb, f_A, dH, dL);
    tsplit(Wout, kD, kD); gemm(dH, dL, bout, f_B, kD, kD, 1.f);
    softmax_k<<<kN / 4, blk, 0, stream>>>(f_B, f_A, kH, kL);   // keys fp32 in f_A
    // Ss
    tsplit(Wss, kD, kSL); gemm(kH, kL, bss, out_Ss, kSL, kD, 1.f);
    // fused cosine scoring (Vs never materialized) -> f_C
    tsplit(Wvs, kD, kSL * kOUT);
    mgemm_k<2, 0, 1><<<dim3(kSL * kOUT / 128, kN / 128), blk, 0, stream>>>(
        kH, kL, wTH, wTL, bvs, nullptr, nullptr, nullptr, x_in, f_xn, f_C,
        kN, kSL * kOUT, kD, 1.f);
    pick_k<<<kN, blk, 0, stream>>>(f_C, f_A, Wvs, bvs, out_Ss, out_v, out_s);
}

// Round 3
// 2119.094 us; speedup vs baseline: 2.1050x; 1.0333x over previous
//
#include <hip/hip_runtime.h>
#include <math.h>

namespace {
constexpr int kD   = 512;
constexpr int kN   = 8192;
constexpr int kS   = 1024;
constexpr int kHD  = 64;
constexpr int kFF  = 2048;
constexpr int kSL  = 512;
constexpr int kOUT = 32;
}

typedef __bf16 bf16x8 __attribute__((ext_vector_type(8)));
typedef float  f32x4  __attribute__((ext_vector_type(4)));

__device__ inline unsigned short f2bf(float x) {
    unsigned u = __float_as_uint(x);
    return (unsigned short)((u + 0x7FFF + ((u >> 16) & 1)) >> 16);
}
__device__ inline void split2(float x, unsigned short& h, unsigned short& l) {
    unsigned u = __float_as_uint(x);
    unsigned hb = (u + 0x7FFF + ((u >> 16) & 1)) >> 16;
    h = (unsigned short)hb;
    float hf = __uint_as_float(hb << 16);
    l = f2bf(x - hf);
}

// =====================================================================
// 256x256 split-precision MFMA GEMM (big-N GEMMs: score, FFN1).
// 8 waves (wave tile 128x64), BK=32, double-buffered LDS (128KB),
// counted vmcnt(8) prefetch, raw barriers, swizzled LDS slots,
// bijective XCD blockIdx swizzle.
// MODE 0: C fp32 (+bias/relu/alpha). MODE 1: hi/lo bf16 planes out.
// MODE 2: fused cosine-score epilogue.
// =====================================================================
template<int MODE, int RELU, int HAS_BIAS>
__global__ __launch_bounds__(512, 2)
void mgemm256_k(const unsigned short* __restrict__ Ah, const unsigned short* __restrict__ Al,
                const unsigned short* __restrict__ Bh, const unsigned short* __restrict__ Bl,
                const float* __restrict__ bias, float* __restrict__ C,
                unsigned short* __restrict__ Ch, unsigned short* __restrict__ Cl,
                const float* __restrict__ X, const float* __restrict__ XN,
                float* __restrict__ SC,
                int M, int N, int K, float alpha)
{
    __shared__ uint4 smem4[8192];           // 128 KB: 2 bufs x (Ah|Al|Bh|Bl x 16KB)
    unsigned char* smem = (unsigned char*)smem4;
    const int tid = threadIdx.x, lane = tid & 63, w = tid >> 6;

    // bijective XCD swizzle (nwg % 8 == 0 for all our grids)
    const int gx = gridDim.x;
    int bid = blockIdx.y * gx + blockIdx.x;
    const int nwg = gx * gridDim.y;
    bid = (bid & 7) * (nwg >> 3) + (bid >> 3);
    const int bx = bid % gx, by = bid / gx;
    const int brow = by * 256, bcol = bx * 256;
    const int wr = (w >> 2) * 128, wc = (w & 3) * 64;
    const size_t K2 = (size_t)K * 2;

    // ---- staging: wave w stages plane (w>>1), half (w&1); 8 x 1KB issues ----
    const int p = w >> 1, hf = w & 1;
    const unsigned short* SP = (p == 0) ? Ah : (p == 1) ? Al : (p == 2) ? Bh : Bl;
    const int rbase = (p < 2) ? brow : bcol;
    // inverse swizzle on the global source: chunk c so that it lands at slot l&3
    const int cch = ((lane & 3) - ((lane >> 3) & 3)) & 3;
    const unsigned char* src0 = (const unsigned char*)SP
        + (size_t)(rbase + hf * 128 + (lane >> 2)) * K2 + (cch << 4);
    const int ldsw0 = (p << 14) + (hf << 13);

    // ---- fragment read addressing (swizzled slot = (lg + (lm>>1)) & 3) ----
    const int lm = lane & 15, lg = lane >> 4;
    const int sw = ((lg + (lm >> 1)) & 3) << 4;
    const int aoff = (wr + lm) * 64 + sw;            // + m*1024 (+16384 for lo)
    const int boff = 32768 + (wc + lm) * 64 + sw;    // + n*1024 (+16384 for lo)

    f32x4 acc[8][4];
#pragma unroll
    for (int i = 0; i < 8; ++i)
#pragma unroll
        for (int j = 0; j < 4; ++j) acc[i][j] = (f32x4)(0.f);

    auto stage = [&](int bufo_, int t_) {
        const unsigned char* s_ = src0 + (size_t)t_ * 64;
#pragma unroll
        for (int j = 0; j < 8; ++j)
            __builtin_amdgcn_global_load_lds(
                (const __attribute__((address_space(1))) unsigned int*)(s_ + (size_t)j * 16 * K2),
                (__attribute__((address_space(3))) unsigned int*)(smem + bufo_ + ldsw0 + j * 1024),
                16, 0, 0);
    };

    const int nt = K >> 5;
    stage(0, 0);
    for (int t = 0; t < nt; ++t) {
        if (t + 1 < nt) {
            stage(((t + 1) & 1) << 16, t + 1);
            asm volatile("s_waitcnt vmcnt(8)" ::: "memory");   // old 8 done; new 8 in flight
        } else {
            asm volatile("s_waitcnt vmcnt(0)" ::: "memory");
        }
        __builtin_amdgcn_s_barrier();
        __builtin_amdgcn_sched_barrier(0);
        const unsigned char* base = smem + ((t & 1) << 16);
        bf16x8 bh[4], bl[4];
#pragma unroll
        for (int n = 0; n < 4; ++n) {
            bh[n] = *(const bf16x8*)(base + boff + n * 1024);
            bl[n] = *(const bf16x8*)(base + boff + 16384 + n * 1024);
        }
#pragma unroll
        for (int m = 0; m < 8; ++m) {
            bf16x8 ah = *(const bf16x8*)(base + aoff + m * 1024);
            bf16x8 al = *(const bf16x8*)(base + aoff + 16384 + m * 1024);
#pragma unroll
            for (int n = 0; n < 4; ++n) {
                acc[m][n] = __builtin_amdgcn_mfma_f32_16x16x32_bf16(al, bh[n], acc[m][n], 0, 0, 0);
                acc[m][n] = __builtin_amdgcn_mfma_f32_16x16x32_bf16(ah, bl[n], acc[m][n], 0, 0, 0);
                acc[m][n] = __builtin_amdgcn_mfma_f32_16x16x32_bf16(ah, bh[n], acc[m][n], 0, 0, 0);
            }
        }
        __builtin_amdgcn_sched_barrier(0);
        __builtin_amdgcn_s_barrier();
    }

    if (MODE == 0 || MODE == 1) {
#pragma unroll
        for (int n = 0; n < 4; ++n) {
            const int colg = bcol + wc + n * 16 + lm;
            const float bv = HAS_BIAS ? bias[colg] : 0.f;
#pragma unroll
            for (int m = 0; m < 8; ++m) {
                const int rowb = brow + wr + m * 16 + lg * 4;
#pragma unroll
                for (int r = 0; r < 4; ++r) {
                    float v = alpha * acc[m][n][r] + bv;
                    if (RELU) v = fmaxf(v, 0.f);
                    if (MODE == 0) {
                        C[(size_t)(rowb + r) * N + colg] = v;
                    } else {
                        unsigned short h, l;
                        split2(v, h, l);
                        Ch[(size_t)(rowb + r) * N + colg] = h;
                        Cl[(size_t)(rowb + r) * N + colg] = l;
                    }
                }
            }
        }
    } else {
        float bv[4];
#pragma unroll
        for (int n = 0; n < 4; ++n) bv[n] = bias[bcol + wc + n * 16 + lm];
        const int slot0 = (bcol + wc) >> 5;
#pragma unroll
        for (int m = 0; m < 8; ++m) {
#pragma unroll
            for (int r = 0; r < 4; ++r) {
                const int row = brow + wr + m * 16 + lg * 4 + r;
                const float x0 = X[(size_t)row * kOUT + lm];
                const float x1 = X[(size_t)row * kOUT + 16 + lm];
                const float xn = XN[row];
#pragma unroll
                for (int s = 0; s < 2; ++s) {
                    const float v0 = acc[m][2 * s][r]     + bv[2 * s];
                    const float v1 = acc[m][2 * s + 1][r] + bv[2 * s + 1];
                    float pd = v0 * x0 + v1 * x1;
                    float pn = v0 * v0 + v1 * v1;
                    pd += __shfl_xor(pd, 1); pd += __shfl_xor(pd, 2);
                    pd += __shfl_xor(pd, 4); pd += __shfl_xor(pd, 8);
                    pn += __shfl_xor(pn, 1); pn += __shfl_xor(pn, 2);
                    pn += __shfl_xor(pn, 4); pn += __shfl_xor(pn, 8);
                    if (lm == 0)
                        SC[(size_t)row * kSL + slot0 + s] = pd / (sqrtf(pn) * xn);
                }
            }
        }
    }
}

// =====================================================================
// 128x128 split-precision MFMA GEMM (N=512 GEMMs). As round 2 + XCD swizzle.
// =====================================================================
template<int MODE, int RELU, int HAS_BIAS>
__global__ __launch_bounds__(256)
void mgemm_k(const unsigned short* __restrict__ Ah, const unsigned short* __restrict__ Al,
             const unsigned short* __restrict__ Bh, const unsigned short* __restrict__ Bl,
             const float* __restrict__ bias, float* __restrict__ C,
             unsigned short* __restrict__ Ch, unsigned short* __restrict__ Cl,
             int M, int N, int K, float alpha)
{
    __shared__ uint4 smem_u4[4096];
    unsigned char* smem = (unsigned char*)smem_u4;
    const int tid  = threadIdx.x;
    const int lane = tid & 63;
    const int w    = tid >> 6;
    const int gx = gridDim.x;
    int bid = blockIdx.y * gx + blockIdx.x;
    const int nwg = gx * gridDim.y;
    bid = (bid & 7) * (nwg >> 3) + (bid >> 3);
    const int bxs = bid % gx, bys = bid / gx;
    const int brow = bys * 128;
    const int bcol = bxs * 128;
    const int wr = (w >> 1) * 64, wc = (w & 1) * 64;
    const size_t Kb = (size_t)K * 2;

    const unsigned short* srcM; int rb;
    if      (w == 0) { srcM = Ah; rb = brow; }
    else if (w == 1) { srcM = Al; rb = brow; }
    else if (w == 2) { srcM = Bh; rb = bcol; }
    else             { srcM = Bl; rb = bcol; }
    const int swzsrc = (((lane & 7) << 4) ^ (((lane >> 3) & 7) << 4));
    const unsigned char* srow = (const unsigned char*)srcM
                              + (size_t)(rb + (lane >> 3)) * Kb + swzsrc;
    unsigned char* dbase = smem + w * 16384;

    const int lm = lane & 15;
    const int lg = lane >> 4;
    const int lswz = (lane & 7);

    f32x4 acc[4][4];
#pragma unroll
    for (int i = 0; i < 4; ++i)
#pragma unroll
        for (int j = 0; j < 4; ++j) acc[i][j] = (f32x4)(0.f);

    for (int k0 = 0; k0 < K; k0 += 64) {
#pragma unroll
        for (int j = 0; j < 16; ++j) {
            const unsigned char* sp = srow + (size_t)(j * 8) * Kb + (size_t)k0 * 2;
            __builtin_amdgcn_global_load_lds(
                (const __attribute__((address_space(1))) unsigned int*)sp,
                (__attribute__((address_space(3))) unsigned int*)(dbase + j * 1024),
                16, 0, 0);
        }
        __syncthreads();
#pragma unroll
        for (int ks = 0; ks < 2; ++ks) {
            const int kf = (((ks << 2) + lg) ^ lswz) << 4;
            bf16x8 bh[4], bl[4];
#pragma unroll
            for (int n = 0; n < 4; ++n) {
                const int r = wc + n * 16 + lm;
                bh[n] = *(const bf16x8*)(smem + 32768 + r * 128 + kf);
                bl[n] = *(const bf16x8*)(smem + 49152 + r * 128 + kf);
            }
#pragma unroll
            for (int m = 0; m < 4; ++m) {
                const int r = wr + m * 16 + lm;
                bf16x8 ah = *(const bf16x8*)(smem +         r * 128 + kf);
                bf16x8 al = *(const bf16x8*)(smem + 16384 + r * 128 + kf);
#pragma unroll
                for (int n = 0; n < 4; ++n) {
                    acc[m][n] = __builtin_amdgcn_mfma_f32_16x16x32_bf16(al, bh[n], acc[m][n], 0, 0, 0);
                    acc[m][n] = __builtin_amdgcn_mfma_f32_16x16x32_bf16(ah, bl[n], acc[m][n], 0, 0, 0);
                    acc[m][n] = __builtin_amdgcn_mfma_f32_16x16x32_bf16(ah, bh[n], acc[m][n], 0, 0, 0);
                }
            }
        }
        __syncthreads();
    }

#pragma unroll
    for (int n = 0; n < 4; ++n) {
        const int colg = bcol + wc + n * 16 + lm;
        const float bv = HAS_BIAS ? bias[colg] : 0.f;
#pragma unroll
        for (int m = 0; m < 4; ++m) {
            const int rowb = brow + wr + m * 16 + lg * 4;
#pragma unroll
            for (int r = 0; r < 4; ++r) {
                float v = alpha * acc[m][n][r] + bv;
                if (RELU) v = fmaxf(v, 0.f);
                if (MODE == 0) {
                    C[(size_t)(rowb + r) * N + colg] = v;
                } else {
                    unsigned short h, l;
                    split2(v, h, l);
                    Ch[(size_t)(rowb + r) * N + colg] = h;
                    Cl[(size_t)(rowb + r) * N + colg] = l;
                }
            }
        }
    }
}

// ---------------------------------------------- weight transpose + split
__global__ __launch_bounds__(256)
void tsplit_k(const float* __restrict__ W, unsigned short* __restrict__ TH,
              unsigned short* __restrict__ TL, int K, int N)
{
    __shared__ float t[32][33];
    const int tid = threadIdx.x;
    const int n0 = blockIdx.x * 32, k0 = blockIdx.y * 32;
    {
        const int r = tid >> 3, c = (tid & 7) * 4;
        const float4 v = *(const float4*)(W + (size_t)(k0 + r) * N + n0 + c);
        t[r][c] = v.x; t[r][c + 1] = v.y; t[r][c + 2] = v.z; t[r][c + 3] = v.w;
    }
    __syncthreads();
    const int rn = tid >> 3, ck = (tid & 7) * 4;
    unsigned short h[4], l[4];
#pragma unroll
    for (int i = 0; i < 4; ++i) split2(t[ck + i][rn], h[i], l[i]);
    *(ushort4*)(TH + (size_t)(n0 + rn) * K + k0 + ck) = make_ushort4(h[0], h[1], h[2], h[3]);
    *(ushort4*)(TL + (size_t)(n0 + rn) * K + k0 + ck) = make_ushort4(l[0], l[1], l[2], l[3]);
}

// ---------------------------------------------------------- split fp32 -> planes
__global__ __launch_bounds__(256)
void split_k(const float* __restrict__ in, unsigned short* __restrict__ hi,
             unsigned short* __restrict__ lo, int n4)
{
    int i = blockIdx.x * 256 + threadIdx.x;
    const int stride = gridDim.x * 256;
    for (; i < n4; i += stride) {
        const float4 v = *(const float4*)(in + (size_t)i * 4);
        unsigned short h[4], l[4];
        split2(v.x, h[0], l[0]); split2(v.y, h[1], l[1]);
        split2(v.z, h[2], l[2]); split2(v.w, h[3], l[3]);
        *(ushort4*)(hi + (size_t)i * 4) = make_ushort4(h[0], h[1], h[2], h[3]);
        *(ushort4*)(lo + (size_t)i * 4) = make_ushort4(l[0], l[1], l[2], l[3]);
    }
}

// ----------------------------------------------- causal flash attention (fp32)
__global__ __launch_bounds__(256)
void attn_k(const float* __restrict__ Q, const float* __restrict__ K,
            const float* __restrict__ V, float* __restrict__ O)
{
    __shared__ float Qs[64][68];
    __shared__ float Ks[64][68];
    __shared__ float Vs[64][68];
    __shared__ float Ps[64][68];
    const int tid = threadIdx.x;
    const int tr = tid >> 4, tc = tid & 15;
    const int qt = blockIdx.x & 15;
    const int h  = (blockIdx.x >> 4) & 7;
    const int b  = blockIdx.x >> 7;
    const int q0 = qt * 64;
    const float* Qb = Q + ((size_t)(b * kS + q0)) * kD + h * kHD;
    {
        const int r = tid >> 2;
#pragma unroll
        for (int it = 0; it < 4; ++it) {
            const int e0 = ((tid & 3) << 2) + it * 16;
            const float4 q4 = *(const float4*)(Qb + (size_t)r * kD + e0);
            Qs[e0 + 0][r] = q4.x; Qs[e0 + 1][r] = q4.y;
            Qs[e0 + 2][r] = q4.z; Qs[e0 + 3][r] = q4.w;
        }
    }
    float m[4], l[4], acc[4][4];
#pragma unroll
    for (int i = 0; i < 4; ++i) {
        m[i] = -INFINITY; l[i] = 0.f;
#pragma unroll
        for (int j = 0; j < 4; ++j) acc[i][j] = 0.f;
    }
    for (int j0 = 0; j0 <= q0; j0 += 64) {
        const float* Kb = K + ((size_t)(b * kS + j0)) * kD + h * kHD;
        const float* Vb = V + ((size_t)(b * kS + j0)) * kD + h * kHD;
        __syncthreads();
        {
            const int c = tid >> 2;
#pragma unroll
            for (int it = 0; it < 4; ++it) {
                const int e0 = ((tid & 3) << 2) + it * 16;
                const float4 k4 = *(const float4*)(Kb + (size_t)c * kD + e0);
                Ks[e0 + 0][c] = k4.x; Ks[e0 + 1][c] = k4.y;
                Ks[e0 + 2][c] = k4.z; Ks[e0 + 3][c] = k4.w;
                *(float4*)&Vs[c][e0] = *(const float4*)(Vb + (size_t)c * kD + e0);
            }
        }
        __syncthreads();
        float s[4][4];
#pragma unroll
        for (int i = 0; i < 4; ++i)
#pragma unroll
            for (int j = 0; j < 4; ++j) s[i][j] = 0.f;
        for (int e = 0; e < 64; ++e) {
            float qa[4], kb[4];
            *(float4*)&qa[0] = *(const float4*)&Qs[e][tr * 4];
            *(float4*)&kb[0] = *(const float4*)&Ks[e][tc * 4];
#pragma unroll
            for (int i = 0; i < 4; ++i)
#pragma unroll
                for (int j = 0; j < 4; ++j)
                    s[i][j] = fmaf(qa[i], kb[j], s[i][j]);
        }
        if (j0 == q0) {
#pragma unroll
            for (int i = 0; i < 4; ++i)
#pragma unroll
                for (int j = 0; j < 4; ++j)
                    if (tc * 4 + j > tr * 4 + i) s[i][j] = -INFINITY;
        }
#pragma unroll
        for (int i = 0; i < 4; ++i) {
            float rm = fmaxf(fmaxf(s[i][0], s[i][1]), fmaxf(s[i][2], s[i][3]));
            rm = fmaxf(rm, __shfl_xor(rm, 1));
            rm = fmaxf(rm, __shfl_xor(rm, 2));
            rm = fmaxf(rm, __shfl_xor(rm, 4));
            rm = fmaxf(rm, __shfl_xor(rm, 8));
            const float mn = fmaxf(m[i], rm);
            const float co = expf(m[i] - mn);
            float ps = 0.f;
#pragma unroll
            for (int j = 0; j < 4; ++j) { s[i][j] = expf(s[i][j] - mn); ps += s[i][j]; }
            ps += __shfl_xor(ps, 1); ps += __shfl_xor(ps, 2);
            ps += __shfl_xor(ps, 4); ps += __shfl_xor(ps, 8);
            l[i] = l[i] * co + ps;
            m[i] = mn;
#pragma unroll
            for (int j = 0; j < 4; ++j) acc[i][j] *= co;
            *(float4*)&Ps[tr * 4 + i][tc * 4] = make_float4(s[i][0], s[i][1], s[i][2], s[i][3]);
        }
        __syncthreads();
        for (int c = 0; c < 64; ++c) {
            const float4 v4 = *(const float4*)&Vs[c][tc * 4];
#pragma unroll
            for (int i = 0; i < 4; ++i) {
                const float p = Ps[tr * 4 + i][c];
                acc[i][0] = fmaf(p, v4.x, acc[i][0]);
                acc[i][1] = fmaf(p, v4.y, acc[i][1]);
                acc[i][2] = fmaf(p, v4.z, acc[i][2]);
                acc[i][3] = fmaf(p, v4.w, acc[i][3]);
            }
        }
    }
    float* Ob = O + ((size_t)(b * kS + q0)) * kD + h * kHD;
#pragma unroll
    for (int i = 0; i < 4; ++i) {
        const float inv = 1.0f / l[i];
        *(float4*)(Ob + (size_t)(tr * 4 + i) * kD + tc * 4) =
            make_float4(acc[i][0] * inv, acc[i][1] * inv, acc[i][2] * inv, acc[i][3] * inv);
    }
}

// ---------------------------------------------------------- LayerNorm (+planes)
__global__ __launch_bounds__(256)
void ln_k(const float* __restrict__ a, const float* __restrict__ b,
          const float* __restrict__ sc, const float* __restrict__ bi,
          float* __restrict__ out, unsigned short* __restrict__ oh,
          unsigned short* __restrict__ ol)
{
    const int w = threadIdx.x >> 6, lane = threadIdx.x & 63;
    const size_t row = (size_t)blockIdx.x * 4 + w;
    const float* ap = a + row * kD;
    float x[8];
    *(float4*)&x[0] = *(const float4*)(ap + lane * 8);
    *(float4*)&x[4] = *(const float4*)(ap + lane * 8 + 4);
    if (b) {
        const float* bp = b + row * kD;
        float y[8];
        *(float4*)&y[0] = *(const float4*)(bp + lane * 8);
        *(float4*)&y[4] = *(const float4*)(bp + lane * 8 + 4);
#pragma unroll
        for (int k = 0; k < 8; ++k) x[k] += y[k];
    }
    float s = 0.f;
#pragma unroll
    for (int k = 0; k < 8; ++k) s += x[k];
    for (int msk = 1; msk < 64; msk <<= 1) s += __shfl_xor(s, msk);
    const float mean = s * (1.0f / 512.0f);
    float v = 0.f;
#pragma unroll
    for (int k = 0; k < 8; ++k) { const float d = x[k] - mean; v = fmaf(d, d, v); }
    for (int msk = 1; msk < 64; msk <<= 1) v += __shfl_xor(v, msk);
    const float rstd = 1.0f / sqrtf(v * (1.0f / 512.0f) + 1e-6f);
    float o[8]; unsigned short h[8], lo2[8];
#pragma unroll
    for (int k = 0; k < 8; ++k) {
        const int col = lane * 8 + k;
        o[k] = (x[k] - mean) * rstd * sc[col] + bi[col];
        split2(o[k], h[k], lo2[k]);
    }
    *(float4*)(out + row * kD + lane * 8)     = *(const float4*)&o[0];
    *(float4*)(out + row * kD + lane * 8 + 4) = *(const float4*)&o[4];
    *(ushort4*)(oh + row * kD + lane * 8)     = make_ushort4(h[0], h[1], h[2], h[3]);
    *(ushort4*)(oh + row * kD + lane * 8 + 4) = make_ushort4(h[4], h[5], h[6], h[7]);
    *(ushort4*)(ol + row * kD + lane * 8)     = make_ushort4(lo2[0], lo2[1], lo2[2], lo2[3]);
    *(ushort4*)(ol + row * kD + lane * 8 + 4) = make_ushort4(lo2[4], lo2[5], lo2[6], lo2[7]);
}

// ---------------------------------------------------------- row softmax (+planes)
__global__ __launch_bounds__(256)
void softmax_k(const float* __restrict__ in, float* __restrict__ out,
               unsigned short* __restrict__ oh, unsigned short* __restrict__ ol)
{
    const int w = threadIdx.x >> 6, lane = threadIdx.x & 63;
    const size_t row = (size_t)blockIdx.x * 4 + w;
    const float* ip = in + row * kD;
    float x[8];
    *(float4*)&x[0] = *(const float4*)(ip + lane * 8);
    *(float4*)&x[4] = *(const float4*)(ip + lane * 8 + 4);
    float mx = x[0];
#pragma unroll
    for (int k = 1; k < 8; ++k) mx = fmaxf(mx, x[k]);
    for (int msk = 1; msk < 64; msk <<= 1) mx = fmaxf(mx, __shfl_xor(mx, msk));
    float s = 0.f;
#pragma unroll
    for (int k = 0; k < 8; ++k) { x[k] = expf(x[k] - mx); s += x[k]; }
    for (int msk = 1; msk < 64; msk <<= 1) s += __shfl_xor(s, msk);
    const float inv = 1.0f / s;
    unsigned short h[8], lo2[8];
#pragma unroll
    for (int k = 0; k < 8; ++k) { x[k] *= inv; split2(x[k], h[k], lo2[k]); }
    *(float4*)(out + row * kD + lane * 8)     = *(const float4*)&x[0];
    *(float4*)(out + row * kD + lane * 8 + 4) = *(const float4*)&x[4];
    *(ushort4*)(oh + row * kD + lane * 8)     = make_ushort4(h[0], h[1], h[2], h[3]);
    *(ushort4*)(oh + row * kD + lane * 8 + 4) = make_ushort4(h[4], h[5], h[6], h[7]);
    *(ushort4*)(ol + row * kD + lane * 8)     = make_ushort4(lo2[0], lo2[1], lo2[2], lo2[3]);
    *(ushort4*)(ol + row * kD + lane * 8 + 4) = make_ushort4(lo2[4], lo2[5], lo2[6], lo2[7]);
}

// ---------------------------------------------------------- ||x_row||
__global__ __launch_bounds__(256)
void xnorm_k(const float* __restrict__ X, float* __restrict__ XN)
{
    const int tid = threadIdx.x;
    const int row = blockIdx.x * 8 + (tid >> 5);
    const int o = tid & 31;
    const float v = X[(size_t)row * kOUT + o];
    float s = v * v;
    s += __shfl_xor(s, 1); s += __shfl_xor(s, 2); s += __shfl_xor(s, 4);
    s += __shfl_xor(s, 8); s += __shfl_xor(s, 16);
    if (o == 0) XN[row] = sqrtf(s);
}

// ------------------------------------- argmax + gather winning slot column
__global__ __launch_bounds__(256)
void pick_k(const float* __restrict__ scores, const float* __restrict__ keys,
            const float* __restrict__ Wvs, const float* __restrict__ bvs,
            const float* __restrict__ Ss, float* __restrict__ vout,
            float* __restrict__ sout)
{
    const int n = blockIdx.x;
    const int tid = threadIdx.x;
    __shared__ float sv[256];
    __shared__ int   si[256];
    __shared__ float ks[512];
    __shared__ float red[256];
    const float s0 = scores[(size_t)n * kSL + tid];
    const float s1 = scores[(size_t)n * kSL + tid + 256];
    float bs; int bi;
    if (s1 > s0) { bs = s1; bi = tid + 256; } else { bs = s0; bi = tid; }
    sv[tid] = bs; si[tid] = bi;
    ks[tid] = keys[(size_t)n * kD + tid];
    ks[tid + 256] = keys[(size_t)n * kD + tid + 256];
    __syncthreads();
    for (int off = 128; off > 0; off >>= 1) {
        if (tid < off) {
            const float ov = sv[tid + off]; const int oi = si[tid + off];
            if (ov > sv[tid] || (ov == sv[tid] && oi < si[tid])) { sv[tid] = ov; si[tid] = oi; }
        }
        __syncthreads();
    }
    const int idx = si[0];
    const int o = tid & 31;
    const int seg = tid >> 5;
    const float* Wc = Wvs + (size_t)idx * kOUT + o;
    float part = 0.f;
    for (int d = seg * 64; d < seg * 64 + 64; ++d)
        part = fmaf(ks[d], Wc[(size_t)d * (kSL * kOUT)], part);
    red[tid] = part;
    __syncthreads();
    if (tid < 32) {
        float t = red[tid];
#pragma unroll
        for (int ss = 1; ss < 8; ++ss) t += red[tid + 32 * ss];
        vout[(size_t)n * kOUT + tid] = t + bvs[idx * kOUT + tid];
    }
    if (tid == 0) sout[n] = Ss[(size_t)n * kSL + idx];
}

// ------------------------------------------------------------------ host
extern "C" void kernel_launch(void* const* d_in, const int* in_sizes, int n_in,
                              void* d_out, int out_size, void* d_ws, size_t ws_size,
                              hipStream_t stream)
{
    (void)in_sizes; (void)n_in; (void)out_size; (void)ws_size;
    const float* s_in = (const float*)d_in[0];
    const float* x_in = (const float*)d_in[1];
    const float* t_in = (const float*)d_in[2];
    const float* Wq   = (const float*)d_in[3];
    const float* Wk   = (const float*)d_in[4];
    const float* Wv   = (const float*)d_in[5];
    const float* Wo   = (const float*)d_in[6];
    const float* cWv  = (const float*)d_in[9];
    const float* cWo  = (const float*)d_in[10];
    const float* ln1s = (const float*)d_in[11];
    const float* ln1b = (const float*)d_in[12];
    const float* ln2s = (const float*)d_in[13];
    const float* ln2b = (const float*)d_in[14];
    const float* ln3s = (const float*)d_in[15];
    const float* ln3b = (const float*)d_in[16];
    const float* W1   = (const float*)d_in[17];
    const float* b1   = (const float*)d_in[18];
    const float* W2   = (const float*)d_in[19];
    const float* b2   = (const float*)d_in[20];
    const float* lnfs = (const float*)d_in[21];
    const float* lnfb = (const float*)d_in[22];
    const float* Wout = (const float*)d_in[23];
    const float* bout = (const float*)d_in[24];
    const float* Wvs  = (const float*)d_in[25];
    const float* bvs  = (const float*)d_in[26];
    const float* Wss  = (const float*)d_in[27];
    const float* bss  = (const float*)d_in[28];

    float* out_v  = (float*)d_out;
    float* out_s  = out_v + (size_t)kN * kOUT;
    float* out_Ss = out_s + kN;

    unsigned char* w8 = (unsigned char*)d_ws;
    const size_t MD = (size_t)kN * kD;
    float* f_dec = (float*)w8;
    float* f_A   = f_dec + MD;
    float* f_B   = f_A + MD;
    float* f_C   = f_B + MD;
    float* f_xn  = f_C + MD;
    unsigned short* dH = (unsigned short*)(f_xn + kN);
    unsigned short* dL = dH + MD;
    unsigned short* hH = dL + MD;
    unsigned short* hL = hH + (size_t)kN * kFF;
    unsigned short* wTH = hL + (size_t)kN * kFF;
    unsigned short* wTL = wTH + (size_t)kSL * kOUT * kD;
    unsigned short* sH = hH;
    unsigned short* sL = hL;
    unsigned short* kH = hH + MD;
    unsigned short* kL = hL + MD;

    const dim3 blk(256);
    const dim3 blk512(512);
    const size_t DD = (size_t)kD * kD;

    auto tsplit = [&](const float* W, int K, int N) {
        tsplit_k<<<dim3(N / 32, K / 32), blk, 0, stream>>>(W, wTH, wTL, K, N);
    };
    auto gemm = [&](const unsigned short* aH, const unsigned short* aL,
                    const float* bias, float* out, int N, int K, float alpha) {
        if (bias)
            mgemm_k<0, 0, 1><<<dim3(N / 128, kN / 128), blk, 0, stream>>>(
                aH, aL, wTH, wTL, bias, out, nullptr, nullptr, kN, N, K, alpha);
        else
            mgemm_k<0, 0, 0><<<dim3(N / 128, kN / 128), blk, 0, stream>>>(
                aH, aL, wTH, wTL, nullptr, out, nullptr, nullptr, kN, N, K, alpha);
    };

    xnorm_k<<<kN / 8, blk, 0, stream>>>(x_in, f_xn);
    split_k<<<1024, blk, 0, stream>>>(s_in, dH, dL, (int)(MD / 4));

    const float* cur = s_in;
    for (int l = 0; l < 2; ++l) {
        const size_t wo = (size_t)l * DD;
        // self-attention
        tsplit(Wq + wo, kD, kD); gemm(dH, dL, nullptr, f_A, kD, kD, 0.125f);
        tsplit(Wk + wo, kD, kD); gemm(dH, dL, nullptr, f_B, kD, kD, 1.f);
        tsplit(Wv + wo, kD, kD); gemm(dH, dL, nullptr, f_C, kD, kD, 1.f);
        attn_k<<<1024, blk, 0, stream>>>(f_A, f_B, f_C, f_A);
        split_k<<<1024, blk, 0, stream>>>(f_A, sH, sL, (int)(MD / 4));
        tsplit(Wo + wo, kD, kD); gemm(sH, sL, nullptr, f_B, kD, kD, 1.f);
        ln_k<<<kN / 4, blk, 0, stream>>>(cur, f_B, ln1s + l * kD, ln1b + l * kD, f_dec, dH, dL);
        // cross-attention (eye mask) == (t @ cWv) @ cWo
        split_k<<<1024, blk, 0, stream>>>(t_in, sH, sL, (int)(MD / 4));
        tsplit(cWv + wo, kD, kD); gemm(sH, sL, nullptr, f_A, kD, kD, 1.f);
        split_k<<<1024, blk, 0, stream>>>(f_A, sH, sL, (int)(MD / 4));
        tsplit(cWo + wo, kD, kD); gemm(sH, sL, nullptr, f_A, kD, kD, 1.f);
        ln_k<<<kN / 4, blk, 0, stream>>>(f_dec, f_A, ln2s + l * kD, ln2b + l * kD, f_dec, dH, dL);
        // FFN (hidden as bf16 hi/lo planes); FFN1 on the 256x256 kernel
        tsplit(W1 + (size_t)l * kD * kFF, kD, kFF);
        mgemm256_k<1, 1, 1><<<dim3(kFF / 256, kN / 256), blk512, 0, stream>>>(
            dH, dL, wTH, wTL, b1 + (size_t)l * kFF, nullptr, hH, hL,
            nullptr, nullptr, nullptr, kN, kFF, kD, 1.f);
        tsplit(W2 + (size_t)l * kFF * kD, kFF, kD);
        gemm(hH, hL, b2 + (size_t)l * kD, f_A, kD, kFF, 1.f);
        ln_k<<<kN / 4, blk, 0, stream>>>(f_dec, f_A, ln3s + l * kD, ln3b + l * kD, f_dec, dH, dL);
        cur = f_dec;
    }
    // final LN -> logits -> keys
    ln_k<<<kN / 4, blk, 0, stream>>>(f_dec, nullptr, lnfs, lnfb, f_A, dH, dL);
    tsplit(Wout, kD, kD); gemm(dH, dL, bout, f_B, kD, kD, 1.f);
    softmax_k<<<kN / 4, blk, 0, stream>>>(f_B, f_A, kH, kL);   // keys fp32 in f_A
    // Ss
    tsplit(Wss, kD, kSL); gemm(kH, kL, bss, out_Ss, kSL, kD, 1.f);
    // fused cosine scoring on the 256x256 kernel -> f_C
    tsplit(Wvs, kD, kSL * kOUT);
    mgemm256_k<2, 0, 1><<<dim3(kSL * kOUT / 256, kN / 256), blk512, 0, stream>>>(
        kH, kL, wTH, wTL, bvs, nullptr, nullptr, nullptr, x_in, f_xn, f_C,
        kN, kSL * kOUT, kD, 1.f);
    pick_k<<<kN, blk, 0, stream>>>(f_C, f_A, Wvs, bvs, out_Ss, out_v, out_s);
}